// Round 5
// baseline (587.401 us; speedup 1.0000x reference)
//
#include <hip/hip_runtime.h>
#include <hip/hip_bf16.h>

// GCN 2-layer forward. CSR pull-aggregation, wave-per-node gathers.
// R5: (1) STALL-ONCE A-HOIST in gemm1 — vmcnt retires IN-ORDER, so any
// B-fragment wait drains older A-prefetches; fix is issuing ALL A-loads of a
// K-half before any B-load (one ~900cyc stall per half instead of per step).
// (2) fill/gemm block roles INTERLEAVED 4:1 by blockIdx%5 so both run
// concurrently on every CU for the whole dispatch (contiguous ranges were
// near-serial due to in-order block dispatch). (3) agg1/agg2 gather MLP
// deepened to 16/32 rows in flight via weight-masked clamped gathers.
// N=100000, F_IN=512, HID=128, C=40, E=1.6M

#define F_IN 512
#define HID  128
#define NC   40
#define NCP  48   // padded h2 row: 96 B = exactly two 64 B lines, 16 B aligned

typedef __attribute__((ext_vector_type(8))) short bf16x8;
typedef __attribute__((ext_vector_type(4))) float f32x4v;

__device__ __forceinline__ ushort f2bf(float f) {
    unsigned r;
    asm("v_cvt_pk_bf16_f32 %0, %1, %1" : "=v"(r) : "v"(f));   // RNE, 1 instr
    return (ushort)r;
}
__device__ __forceinline__ unsigned cvtpk(float a, float b) {
    unsigned r;
    asm("v_cvt_pk_bf16_f32 %0, %1, %2" : "=v"(r) : "v"(a), "v"(b));
    return r;
}
__device__ __forceinline__ float bf2f(ushort u) {
    return __uint_as_float((unsigned)u << 16);
}
__device__ __forceinline__ bf16x8 cvt8(float4 lo, float4 hi) {
    union { unsigned u[4]; bf16x8 v; } t;
    t.u[0] = cvtpk(lo.x, lo.y); t.u[1] = cvtpk(lo.z, lo.w);
    t.u[2] = cvtpk(hi.x, hi.y); t.u[3] = cvtpk(hi.z, hi.w);
    return t.v;
}

// ---------------- degree count + rank (real edges) + weight pack ------------
__global__ void prep_k(const int* __restrict__ dst, int E, int EB,
                       unsigned* __restrict__ cnt, int* __restrict__ rank,
                       const float* __restrict__ W1, const float* __restrict__ W2,
                       ushort* __restrict__ W1p, ushort* __restrict__ W2p) {
    int b = blockIdx.x;
    if (b < EB) {
        int t = b * 256 + threadIdx.x;
        if (t < E) rank[t] = (int)atomicAdd(&cnt[dst[t]], 1u);
        return;
    }
    int t = (b - EB) * 256 + threadIdx.x;
    if (t < 65536) {
        int j = t & 7, n = (t >> 3) & 127, kb = (t >> 10) & 3, s = t >> 12;
        int k = s * 32 + kb * 8 + j;
        W1p[t] = f2bf(W1[(size_t)k * HID + n]);
    } else {
        int q = t - 65536;
        if (q < 6144) {
            int j = q & 7;
            int i2 = q >> 3;
            int n = i2 % 48;
            int i3 = i2 / 48;
            int kb = i3 & 3, ks = i3 >> 2;
            int k = ks * 32 + kb * 8 + j;
            float v = (n < NC) ? W2[(size_t)k * NC + n] : 0.f;
            W2p[q] = f2bf(v);
        }
    }
}

// ---------------- block-local exclusive scan (shfl-based) + fused dis -------
__global__ __launch_bounds__(1024) void scan_block(const unsigned* __restrict__ cnt,
                                                   unsigned* __restrict__ offs,
                                                   unsigned* __restrict__ bsums,
                                                   float* __restrict__ dis, int N) {
    int tid = threadIdx.x;
    int i = blockIdx.x * 1024 + tid;
    unsigned v = (i < N) ? cnt[i] : 0u;
    if (i < N) dis[i] = rsqrtf((float)v + 1.0f);   // +1 = self loop
    int lane = tid & 63, w = tid >> 6;
    unsigned s = v;
    #pragma unroll
    for (int d = 1; d < 64; d <<= 1) {
        unsigned t = __shfl_up(s, d, 64);
        if (lane >= d) s += t;
    }
    __shared__ unsigned wt[16];
    if (lane == 63) wt[w] = s;
    __syncthreads();
    unsigned add = 0;
    #pragma unroll
    for (int j = 0; j < 16; j++) add += (j < w) ? wt[j] : 0u;
    unsigned incl = s + add;
    if (i < N) offs[i] = incl - v;                 // exclusive within block
    if (tid == 1023) bsums[blockIdx.x] = incl;     // raw block total
}

// ---------------- add bsums prefix (computed in-block, no serial kernel) ----
__global__ __launch_bounds__(1024) void scan_add2(unsigned* __restrict__ offs,
                                                  const unsigned* __restrict__ bsums,
                                                  int N, unsigned total) {
    int i = blockIdx.x * 1024 + threadIdx.x;
    int lane = threadIdx.x & 63;
    unsigned s = 0;
    for (int j = lane; j < (int)blockIdx.x; j += 64) s += bsums[j];
    #pragma unroll
    for (int d = 1; d < 64; d <<= 1) s += __shfl_xor(s, d, 64);
    if (i < N) offs[i] += s;
    if (i == 0) offs[N] = total;
}

// ------- MERGED, INTERLEAVED: gemm1 (bid%5==0) + fill_csr (other blocks) ----
// gemm1: h1s[N,128] = (bf16(x) @ W1) * dis[row]; 16 rows/wave.
// A is hoisted a FULL K-half at a time (16 float4 loads issued before any
// B-fragment load) -> in-order vmcnt means B-waits never drain A; one HBM
// stall per half. Two halves with unroll-1 keep peak VGPR ~150.
__global__ __launch_bounds__(256, 3) void fill_gemm1(
        const int* __restrict__ src, const int* __restrict__ dst,
        const unsigned* __restrict__ offs, const int* __restrict__ rank,
        int* __restrict__ col, int E, int GB,
        const float* __restrict__ A, const ushort* __restrict__ Bp,
        const float* __restrict__ dis, ushort* __restrict__ C, int N) {
    const int bid = blockIdx.x;
    const int g   = bid / 5;
    const int r5  = bid - g * 5;
    if (!(r5 == 0 && g < GB)) {
        // ---- fill_csr part (atomic-free), 4-of-5 blocks ----
        int gb_before = g + (r5 > 0 ? 1 : 0);
        if (gb_before > GB) gb_before = GB;
        int t = (bid - gb_before) * 256 + threadIdx.x;
        if (t < E) {
            int d = dst[t];
            col[offs[d] + (unsigned)rank[t]] = src[t];
        }
        return;
    }
    // ---- gemm1 part: 16 rows per wave, stall-once A-hoist ----
    const int tid  = threadIdx.x;
    const int wave = tid >> 6;
    const int lane = tid & 63;
    const int quad = lane >> 4;
    const int mr   = lane & 15;
    const int base = (g * 4 + wave) * 16;
    if (base >= N) return;
    const int r0 = base + mr;
    const float* ap0 = A + (size_t)(r0 < N ? r0 : 0) * F_IN + quad * 8;
    const ushort* bp = Bp + quad * 1024 + mr * 8;   // + s*4096 + t*128

    f32x4v acc0[8];
    #pragma unroll
    for (int t = 0; t < 8; t++) acc0[t] = (f32x4v){0.f, 0.f, 0.f, 0.f};

    #pragma unroll 1
    for (int h = 0; h < 2; h++) {
        // hoist: all 16 A-loads of this half issued before any B-load
        float4 av[8][2];
        #pragma unroll
        for (int q = 0; q < 8; q++) {
            av[q][0] = *(const float4*)(ap0 + (h * 8 + q) * 32);
            av[q][1] = *(const float4*)(ap0 + (h * 8 + q) * 32 + 4);
        }
        bf16x8 af[8];
        #pragma unroll
        for (int q = 0; q < 8; q++) af[q] = cvt8(av[q][0], av[q][1]);
        #pragma unroll
        for (int s2 = 0; s2 < 8; s2++) {
            const ushort* bs = bp + (h * 8 + s2) * 4096;
            #pragma unroll
            for (int t = 0; t < 8; t++) {
                bf16x8 bb = *(const bf16x8*)(bs + t * 128);
                acc0[t] = __builtin_amdgcn_mfma_f32_16x16x32_bf16(af[s2], bb, acc0[t], 0, 0, 0);
            }
        }
    }

    // epilogue: C/D layout col=t*16+mr, row=quad*4+rr; scale by dis[row]
    #pragma unroll
    for (int rr = 0; rr < 4; rr++) {
        int ra = base + quad * 4 + rr;
        if (ra < N) {
            float ds = dis[ra];
            #pragma unroll
            for (int t = 0; t < 8; t++)
                C[(size_t)ra * HID + t * 16 + mr] = f2bf(acc0[t][rr] * ds);
        }
    }
}

// ------- agg1: ONE WAVE per node. lane = ni(4) x fl(16). 16 rows in flight. -
// out[node] = bf16( relu( dis[node] * (h1s[node] + sum h1s[s]) + b1 ) )
// Invalid slots clamp to row 0 with weight 0 (unconditional gathers -> MLP).
__global__ __launch_bounds__(256) void agg1_k(const ushort* __restrict__ h,
                                              const int* __restrict__ col,
                                              const unsigned* __restrict__ offs,
                                              const float* __restrict__ dis,
                                              const float* __restrict__ b1,
                                              ushort* __restrict__ out, int N) {
    int node = blockIdx.x * 4 + (threadIdx.x >> 6);
    if (node >= N) return;
    int lane = threadIdx.x & 63;
    int ni = lane >> 4;          // neighbor slot 0..3
    int fl = lane & 15;          // feature group (8 bf16 each)
    const ushort* hb = h + (size_t)fl * 8;
    float a[8] = {0.f, 0.f, 0.f, 0.f, 0.f, 0.f, 0.f, 0.f};
    if (ni == 0) {   // self row
        uint4 v = *(const uint4*)(hb + (size_t)node * HID);
        const ushort* u = (const ushort*)&v;
        #pragma unroll
        for (int j = 0; j < 8; j++) a[j] = bf2f(u[j]);
    }
    unsigned p0 = offs[node], p1 = offs[node + 1];
    int s0, s1, s2, s3;
    float w0, w1, w2, w3;
    #define GETC1(pos, sv, wv) { unsigned q_ = (pos); bool v_ = q_ < p1; \
        sv = v_ ? col[q_] : 0; wv = v_ ? 1.f : 0.f; }
    GETC1(p0 + ni,      s0, w0);
    GETC1(p0 + ni + 4,  s1, w1);
    GETC1(p0 + ni + 8,  s2, w2);
    GETC1(p0 + ni + 12, s3, w3);
    for (unsigned p = p0; p < p1; p += 16) {
        int n0, n1, n2, n3;
        float x0, x1, x2, x3;
        GETC1(p + 16 + ni, n0, x0);
        GETC1(p + 20 + ni, n1, x1);
        GETC1(p + 24 + ni, n2, x2);
        GETC1(p + 28 + ni, n3, x3);
        uint4 v0 = *(const uint4*)(hb + (size_t)s0 * HID);
        uint4 v1 = *(const uint4*)(hb + (size_t)s1 * HID);
        uint4 v2 = *(const uint4*)(hb + (size_t)s2 * HID);
        uint4 v3 = *(const uint4*)(hb + (size_t)s3 * HID);
        const ushort* u0 = (const ushort*)&v0;
        const ushort* u1 = (const ushort*)&v1;
        const ushort* u2 = (const ushort*)&v2;
        const ushort* u3 = (const ushort*)&v3;
        #pragma unroll
        for (int j = 0; j < 8; j++)
            a[j] += (w0 * bf2f(u0[j]) + w1 * bf2f(u1[j]))
                  + (w2 * bf2f(u2[j]) + w3 * bf2f(u3[j]));
        s0 = n0; w0 = x0; s1 = n1; w1 = x1;
        s2 = n2; w2 = x2; s3 = n3; w3 = x3;
    }
    // reduce across the 4 neighbor slots (lane bits 4,5)
    #pragma unroll
    for (int j = 0; j < 8; j++) {
        a[j] += __shfl_xor(a[j], 16);
        a[j] += __shfl_xor(a[j], 32);
    }
    if (ni == 0) {
        float dd = dis[node];
        float4 bb0 = *(const float4*)(b1 + fl * 8);
        float4 bb1 = *(const float4*)(b1 + fl * 8 + 4);
        const float bb[8] = {bb0.x, bb0.y, bb0.z, bb0.w, bb1.x, bb1.y, bb1.z, bb1.w};
        __align__(16) ushort o[8];
        #pragma unroll
        for (int j = 0; j < 8; j++) o[j] = f2bf(fmaxf(a[j] * dd + bb[j], 0.f));
        *(uint4*)(out + (size_t)node * HID + (size_t)fl * 8) = *(const uint4*)o;
    }
}

// ------- GEMM2 MFMA, barrier-free: h2s[N,48p] = (ag1 @ W2) * dis[row] -------
__global__ __launch_bounds__(256) void gemm2_mfma(const ushort* __restrict__ A,
                                                  const ushort* __restrict__ W2p,
                                                  const float* __restrict__ dis,
                                                  ushort* __restrict__ h2, int N) {
    const int tid  = threadIdx.x;
    const int wave = tid >> 6;
    const int lane = tid & 63;
    const int quad = lane >> 4;
    const int mr   = lane & 15;
    const int base = (blockIdx.x * 4 + wave) * 32;
    if (base >= N) return;
    const int r0 = base + mr;
    const int r1 = base + 16 + mr;
    const bool ok0 = r0 < N, ok1 = r1 < N;
    const ushort* ap0 = A + (size_t)(ok0 ? r0 : 0) * HID + quad * 8;
    const ushort* ap1 = A + (size_t)(ok1 ? r1 : 0) * HID + quad * 8;
    const ushort* bp = W2p + quad * 384 + mr * 8;   // + ks*1536 + t*128

    f32x4v acc0[3], acc1[3];
    #pragma unroll
    for (int t = 0; t < 3; t++) {
        acc0[t] = (f32x4v){0.f, 0.f, 0.f, 0.f};
        acc1[t] = (f32x4v){0.f, 0.f, 0.f, 0.f};
    }
    #pragma unroll
    for (int ks = 0; ks < 4; ks++) {
        bf16x8 a0 = *(const bf16x8*)(ap0 + ks * 32);
        bf16x8 a1 = *(const bf16x8*)(ap1 + ks * 32);
        #pragma unroll
        for (int t = 0; t < 3; t++) {
            bf16x8 b = *(const bf16x8*)(bp + ks * 1536 + t * 128);
            acc0[t] = __builtin_amdgcn_mfma_f32_16x16x32_bf16(a0, b, acc0[t], 0, 0, 0);
            acc1[t] = __builtin_amdgcn_mfma_f32_16x16x32_bf16(a1, b, acc1[t], 0, 0, 0);
        }
    }
    #pragma unroll
    for (int rr = 0; rr < 4; rr++) {
        int ra = base + quad * 4 + rr;
        if (ra < N) {
            float ds = dis[ra];
            #pragma unroll
            for (int t = 0; t < 3; t++) {
                int c = t * 16 + mr;
                if (c < NC) h2[(size_t)ra * NCP + c] = f2bf(acc0[t][rr] * ds);
            }
        }
        int rb = base + 16 + quad * 4 + rr;
        if (rb < N) {
            float ds = dis[rb];
            #pragma unroll
            for (int t = 0; t < 3; t++) {
                int c = t * 16 + mr;
                if (c < NC) h2[(size_t)rb * NCP + c] = f2bf(acc1[t][rr] * ds);
            }
        }
    }
}

// ------- agg2 + b2 + log_softmax: ONE WAVE per node. lane = ni(8) x fl(8). --
// 32 rows in flight (weight-masked clamped gathers). h2 rows padded to 48.
__global__ __launch_bounds__(256) void agg2_ls(const ushort* __restrict__ h2,
                                               const int* __restrict__ col,
                                               const unsigned* __restrict__ offs,
                                               const float* __restrict__ dis,
                                               const float* __restrict__ b2,
                                               float* __restrict__ out, int N) {
    int node = blockIdx.x * 4 + (threadIdx.x >> 6);
    if (node >= N) return;
    int lane = threadIdx.x & 63;
    int ni = lane >> 3;          // neighbor slot 0..7
    int fl = lane & 7;           // feature group
    const bool act = fl < 5;     // 5 x 8 = 40 classes
    const ushort* hb = h2 + (size_t)fl * 8;
    float a[8] = {0.f, 0.f, 0.f, 0.f, 0.f, 0.f, 0.f, 0.f};
    if (ni == 0 && act) {   // self row
        uint4 v = *(const uint4*)(hb + (size_t)node * NCP);
        const ushort* u = (const ushort*)&v;
        #pragma unroll
        for (int j = 0; j < 8; j++) a[j] = bf2f(u[j]);
    }
    unsigned p0 = offs[node], p1 = offs[node + 1];
    int s0, s1, s2, s3;
    float w0, w1, w2, w3;
    GETC1(p0 + ni,      s0, w0);
    GETC1(p0 + ni + 8,  s1, w1);
    GETC1(p0 + ni + 16, s2, w2);
    GETC1(p0 + ni + 24, s3, w3);
    for (unsigned p = p0; p < p1; p += 32) {
        int n0, n1, n2, n3;
        float x0, x1, x2, x3;
        GETC1(p + 32 + ni, n0, x0);
        GETC1(p + 40 + ni, n1, x1);
        GETC1(p + 48 + ni, n2, x2);
        GETC1(p + 56 + ni, n3, x3);
        if (act) {
            uint4 v0 = *(const uint4*)(hb + (size_t)s0 * NCP);
            uint4 v1 = *(const uint4*)(hb + (size_t)s1 * NCP);
            uint4 v2 = *(const uint4*)(hb + (size_t)s2 * NCP);
            uint4 v3 = *(const uint4*)(hb + (size_t)s3 * NCP);
            const ushort* u0 = (const ushort*)&v0;
            const ushort* u1 = (const ushort*)&v1;
            const ushort* u2 = (const ushort*)&v2;
            const ushort* u3 = (const ushort*)&v3;
            #pragma unroll
            for (int j = 0; j < 8; j++)
                a[j] += (w0 * bf2f(u0[j]) + w1 * bf2f(u1[j]))
                      + (w2 * bf2f(u2[j]) + w3 * bf2f(u3[j]));
        }
        s0 = n0; w0 = x0; s1 = n1; w1 = x1;
        s2 = n2; w2 = x2; s3 = n3; w3 = x3;
    }
    // reduce across the 8 neighbor slots (lane bits 3,4,5)
    #pragma unroll
    for (int j = 0; j < 8; j++) {
        a[j] += __shfl_xor(a[j], 8);
        a[j] += __shfl_xor(a[j], 16);
        a[j] += __shfl_xor(a[j], 32);
    }
    float dd = dis[node];
    float l[8];
    float m = -1e30f;
    if (act) {
        #pragma unroll
        for (int j = 0; j < 8; j++) {
            l[j] = a[j] * dd + b2[fl * 8 + j];
            m = fmaxf(m, l[j]);
        }
    }
    #pragma unroll
    for (int d = 1; d < 8; d <<= 1) m = fmaxf(m, __shfl_xor(m, d, 8));
    float s = 0.f;
    if (act) {
        #pragma unroll
        for (int j = 0; j < 8; j++) s += __expf(l[j] - m);
    }
    #pragma unroll
    for (int d = 1; d < 8; d <<= 1) s += __shfl_xor(s, d, 8);
    float lse = m + __logf(s);
    if (ni == 0 && act) {
        float* op = out + (size_t)node * NC + fl * 8;
        *(float4*)op       = make_float4(l[0]-lse, l[1]-lse, l[2]-lse, l[3]-lse);
        *(float4*)(op + 4) = make_float4(l[4]-lse, l[5]-lse, l[6]-lse, l[7]-lse);
    }
}

extern "C" void kernel_launch(void* const* d_in, const int* in_sizes, int n_in,
                              void* d_out, int out_size, void* d_ws, size_t ws_size,
                              hipStream_t stream) {
    const float* x  = (const float*)d_in[0];
    const int*   ei = (const int*)d_in[1];
    const float* W1 = (const float*)d_in[2];
    const float* b1 = (const float*)d_in[3];
    const float* W2 = (const float*)d_in[4];
    const float* b2 = (const float*)d_in[5];
    float* out = (float*)d_out;

    const int N = in_sizes[0] / F_IN;     // 100000
    const int E = in_sizes[1] / 2;        // 1600000
    const int* src = ei;
    const int* dst = ei + E;

    // ---- workspace layout ----
    char* ws = (char*)d_ws;
    size_t o = 0;
    unsigned* cnt  = (unsigned*)(ws + o); o += (size_t)N * 4;
    float*    dis  = (float*)   (ws + o); o += (size_t)N * 4;
    unsigned* offs = (unsigned*)(ws + o); o += (size_t)(N + 4) * 4;
    unsigned* bsums= (unsigned*)(ws + o); o += 4096;
    int*      rank = (int*)     (ws + o); o += (size_t)E * 4;            // 6.4 MB
    int*      col  = (int*)     (ws + o); o += (size_t)E * 4;            // 6.4 MB
    o = (o + 15) & ~(size_t)15;
    ushort*   W1p  = (ushort*)  (ws + o); o += (size_t)F_IN * HID * 2;   // 128 KB
    o = (o + 15) & ~(size_t)15;
    ushort*   W2p  = (ushort*)  (ws + o); o += 6144 * 2;                 // 12 KB
    o = (o + 15) & ~(size_t)15;
    ushort*   h1   = (ushort*)  (ws + o); o += (size_t)N * HID * 2;      // 25.6 MB
    o = (o + 15) & ~(size_t)15;
    ushort*   ag1  = (ushort*)  (ws + o); o += (size_t)N * HID * 2;      // 25.6 MB
    o = (o + 15) & ~(size_t)15;
    ushort*   h2   = (ushort*)  (ws + o); o += (size_t)N * NCP * 2;      // 9.6 MB

    const int nb = (N + 1023) / 1024;
    const int EB = (E + 255) / 256;
    const int PB = (65536 + 6144 + 255) / 256;   // 280 pack blocks
    const int GB = (N + 63) / 64;                // gemm1 blocks (16 rows/wave)

    // degree count (with rank capture) + weight pack in one launch
    hipMemsetAsync(cnt, 0, (size_t)N * 4, stream);
    prep_k<<<EB + PB, 256, 0, stream>>>(dst, E, EB, cnt, rank, W1, W2, W1p, W2p);
    scan_block<<<nb, 1024, 0, stream>>>(cnt, offs, bsums, dis, N);
    scan_add2<<<nb, 1024, 0, stream>>>(offs, bsums, N, (unsigned)E);

    // CSR fill (atomic-free) + layer-1 GEMM: ONE dispatch, roles interleaved
    fill_gemm1<<<GB + EB, 256, 0, stream>>>(src, dst, offs, rank, col, E, GB,
                                            x, W1p, dis, h1, N);

    agg1_k<<<(N + 3) / 4, 256, 0, stream>>>(h1, col, offs, dis, b1, ag1, N);

    // layer 2
    gemm2_mfma<<<(N + 127) / 128, 256, 0, stream>>>(ag1, W2p, dis, h2, N);
    agg2_ls<<<(N + 3) / 4, 256, 0, stream>>>(h2, col, offs, dis, b2, out, N);
}

// Round 6
// 545.737 us; speedup vs baseline: 1.0763x; 1.0763x over previous
//
#include <hip/hip_runtime.h>
#include <hip/hip_bf16.h>

// GCN 2-layer forward. CSR pull-aggregation, wave-per-node gathers.
// R6: B OUT OF THE VMEM STREAM. R5 proved (VGPR=32) the compiler re-schedules
// any source-level A-hoist; and B-fragment loads share in-order vmcnt with A,
// so every K-step's B-wait drains the A prefetch ring. Fix: stage W1p in LDS
// (64 KB, two 8-step phases, 1024-thr blocks) -> K-loop VMEM = A only; B via
// ds_read/lgkmcnt. Barrier drains happen 2x per block, not per step.
// gemm2 likewise stages its 12 KB W2p in LDS. fill stays merged (grid-stride,
// 2:1 interleave). N=100000, F_IN=512, HID=128, C=40, E=1.6M

#define F_IN 512
#define HID  128
#define NC   40
#define NCP  48   // padded h2 row: 96 B = exactly two 64 B lines, 16 B aligned

typedef __attribute__((ext_vector_type(8))) short bf16x8;
typedef __attribute__((ext_vector_type(4))) float f32x4v;

__device__ __forceinline__ ushort f2bf(float f) {
    unsigned r;
    asm("v_cvt_pk_bf16_f32 %0, %1, %1" : "=v"(r) : "v"(f));   // RNE, 1 instr
    return (ushort)r;
}
__device__ __forceinline__ unsigned cvtpk(float a, float b) {
    unsigned r;
    asm("v_cvt_pk_bf16_f32 %0, %1, %2" : "=v"(r) : "v"(a), "v"(b));
    return r;
}
__device__ __forceinline__ float bf2f(ushort u) {
    return __uint_as_float((unsigned)u << 16);
}
__device__ __forceinline__ bf16x8 cvt8(float4 lo, float4 hi) {
    union { unsigned u[4]; bf16x8 v; } t;
    t.u[0] = cvtpk(lo.x, lo.y); t.u[1] = cvtpk(lo.z, lo.w);
    t.u[2] = cvtpk(hi.x, hi.y); t.u[3] = cvtpk(hi.z, hi.w);
    return t.v;
}

// ---------------- degree count + rank (real edges) + weight pack ------------
__global__ void prep_k(const int* __restrict__ dst, int E, int EB,
                       unsigned* __restrict__ cnt, int* __restrict__ rank,
                       const float* __restrict__ W1, const float* __restrict__ W2,
                       ushort* __restrict__ W1p, ushort* __restrict__ W2p) {
    int b = blockIdx.x;
    if (b < EB) {
        int t = b * 256 + threadIdx.x;
        if (t < E) rank[t] = (int)atomicAdd(&cnt[dst[t]], 1u);
        return;
    }
    int t = (b - EB) * 256 + threadIdx.x;
    if (t < 65536) {
        int j = t & 7, n = (t >> 3) & 127, kb = (t >> 10) & 3, s = t >> 12;
        int k = s * 32 + kb * 8 + j;
        W1p[t] = f2bf(W1[(size_t)k * HID + n]);
    } else {
        int q = t - 65536;
        if (q < 6144) {
            int j = q & 7;
            int i2 = q >> 3;
            int n = i2 % 48;
            int i3 = i2 / 48;
            int kb = i3 & 3, ks = i3 >> 2;
            int k = ks * 32 + kb * 8 + j;
            float v = (n < NC) ? W2[(size_t)k * NC + n] : 0.f;
            W2p[q] = f2bf(v);
        }
    }
}

// ---------------- block-local exclusive scan (shfl-based) + fused dis -------
__global__ __launch_bounds__(1024) void scan_block(const unsigned* __restrict__ cnt,
                                                   unsigned* __restrict__ offs,
                                                   unsigned* __restrict__ bsums,
                                                   float* __restrict__ dis, int N) {
    int tid = threadIdx.x;
    int i = blockIdx.x * 1024 + tid;
    unsigned v = (i < N) ? cnt[i] : 0u;
    if (i < N) dis[i] = rsqrtf((float)v + 1.0f);   // +1 = self loop
    int lane = tid & 63, w = tid >> 6;
    unsigned s = v;
    #pragma unroll
    for (int d = 1; d < 64; d <<= 1) {
        unsigned t = __shfl_up(s, d, 64);
        if (lane >= d) s += t;
    }
    __shared__ unsigned wt[16];
    if (lane == 63) wt[w] = s;
    __syncthreads();
    unsigned add = 0;
    #pragma unroll
    for (int j = 0; j < 16; j++) add += (j < w) ? wt[j] : 0u;
    unsigned incl = s + add;
    if (i < N) offs[i] = incl - v;                 // exclusive within block
    if (tid == 1023) bsums[blockIdx.x] = incl;     // raw block total
}

// ---------------- add bsums prefix (computed in-block, no serial kernel) ----
__global__ __launch_bounds__(1024) void scan_add2(unsigned* __restrict__ offs,
                                                  const unsigned* __restrict__ bsums,
                                                  int N, unsigned total) {
    int i = blockIdx.x * 1024 + threadIdx.x;
    int lane = threadIdx.x & 63;
    unsigned s = 0;
    for (int j = lane; j < (int)blockIdx.x; j += 64) s += bsums[j];
    #pragma unroll
    for (int d = 1; d < 64; d <<= 1) s += __shfl_xor(s, d, 64);
    if (i < N) offs[i] += s;
    if (i == 0) offs[N] = total;
}

// ------- MERGED: gemm1 (B in LDS) + fill_csr, interleaved 2:1 by bid%3 ------
// gemm blocks: 1024 thr = 16 waves x 16 rows = 256 rows. LDS = 64 KB = half
// of W1p; two phases of 8 K-steps. K-loop VMEM = A-loads ONLY (ring dist 4);
// B via ds_read_b128. fill blocks: grid-stride atomic-free CSR scatter.
__global__ __launch_bounds__(1024, 4) void fillg1(
        const int* __restrict__ src, const int* __restrict__ dst,
        const unsigned* __restrict__ offs, const int* __restrict__ rank,
        int* __restrict__ col, int E, int F,
        const float* __restrict__ A, const ushort* __restrict__ Bp,
        const float* __restrict__ dis, ushort* __restrict__ C, int N) {
    __shared__ ushort Bs[32768];   // 64 KB: 8 K-steps x 4096 elems
    const int bid = blockIdx.x;
    const int tid = threadIdx.x;
    if (bid % 3 == 2) {
        // ---- fill part (atomic-free), grid-stride over edges ----
        const int stride = F * 1024;
        for (int e = (bid / 3) * 1024 + tid; e < E; e += stride) {
            int d = dst[e];
            col[offs[d] + (unsigned)rank[e]] = src[e];
        }
        return;
    }
    // ---- gemm1 part ----
    const int g    = bid - bid / 3;          // gemm block index 0..GB-1
    const int wave = tid >> 6;
    const int lane = tid & 63;
    const int quad = lane >> 4;
    const int mr   = lane & 15;
    const int base = g * 256 + wave * 16;
    const int r0 = base + mr;
    const float* ap0 = A + (size_t)(r0 < N ? r0 : 0) * F_IN + quad * 8;
    const ushort* lbp = Bs + quad * 1024 + mr * 8;   // + sl*4096 + t*128

    // stage phase 0 (W1p elems [0, 32768)): 1024 thr x 4 uint4
    {
        const uint4* bsrc = (const uint4*)Bp;
        uint4* bdst = (uint4*)Bs;
        #pragma unroll
        for (int r = 0; r < 4; r++) bdst[tid + r * 1024] = bsrc[tid + r * 1024];
    }

    f32x4v acc0[8];
    #pragma unroll
    for (int t = 0; t < 8; t++) acc0[t] = (f32x4v){0.f, 0.f, 0.f, 0.f};

    // A prefetch ring, distance 4
    float4 av[4][2];
    #pragma unroll
    for (int b = 0; b < 4; b++) {
        av[b][0] = *(const float4*)(ap0 + b * 32);
        av[b][1] = *(const float4*)(ap0 + b * 32 + 4);
    }
    __syncthreads();   // phase-0 B visible

    // phase 0: steps 0..7
    #pragma unroll
    for (int s = 0; s < 8; s++) {
        bf16x8 fa = cvt8(av[s & 3][0], av[s & 3][1]);
        av[s & 3][0] = *(const float4*)(ap0 + (s + 4) * 32);
        av[s & 3][1] = *(const float4*)(ap0 + (s + 4) * 32 + 4);
        const ushort* bs = lbp + s * 4096;
        #pragma unroll
        for (int t = 0; t < 8; t++) {
            bf16x8 bb = *(const bf16x8*)(bs + t * 128);
            acc0[t] = __builtin_amdgcn_mfma_f32_16x16x32_bf16(fa, bb, acc0[t], 0, 0, 0);
        }
    }
    __syncthreads();   // all waves done reading phase-0 B
    {   // stage phase 1 (W1p elems [32768, 65536))
        const uint4* bsrc = (const uint4*)Bp;
        uint4* bdst = (uint4*)Bs;
        #pragma unroll
        for (int r = 0; r < 4; r++) bdst[tid + r * 1024] = bsrc[4096 + tid + r * 1024];
    }
    __syncthreads();   // phase-1 B visible

    // phase 1: steps 8..15
    #pragma unroll
    for (int s = 8; s < 16; s++) {
        bf16x8 fa = cvt8(av[s & 3][0], av[s & 3][1]);
        if (s < 12) {
            av[s & 3][0] = *(const float4*)(ap0 + (s + 4) * 32);
            av[s & 3][1] = *(const float4*)(ap0 + (s + 4) * 32 + 4);
        }
        const ushort* bs = lbp + (s - 8) * 4096;
        #pragma unroll
        for (int t = 0; t < 8; t++) {
            bf16x8 bb = *(const bf16x8*)(bs + t * 128);
            acc0[t] = __builtin_amdgcn_mfma_f32_16x16x32_bf16(fa, bb, acc0[t], 0, 0, 0);
        }
    }

    // epilogue: C/D layout col=t*16+mr, row=quad*4+rr; scale by dis[row]
    #pragma unroll
    for (int rr = 0; rr < 4; rr++) {
        int ra = base + quad * 4 + rr;
        if (ra < N) {
            float ds = dis[ra];
            #pragma unroll
            for (int t = 0; t < 8; t++)
                C[(size_t)ra * HID + t * 16 + mr] = f2bf(acc0[t][rr] * ds);
        }
    }
}

// ------- agg1: ONE WAVE per node. lane = ni(4) x fl(16). 16 rows in flight. -
__global__ __launch_bounds__(256) void agg1_k(const ushort* __restrict__ h,
                                              const int* __restrict__ col,
                                              const unsigned* __restrict__ offs,
                                              const float* __restrict__ dis,
                                              const float* __restrict__ b1,
                                              ushort* __restrict__ out, int N) {
    int node = blockIdx.x * 4 + (threadIdx.x >> 6);
    if (node >= N) return;
    int lane = threadIdx.x & 63;
    int ni = lane >> 4;          // neighbor slot 0..3
    int fl = lane & 15;          // feature group (8 bf16 each)
    const ushort* hb = h + (size_t)fl * 8;
    float a[8] = {0.f, 0.f, 0.f, 0.f, 0.f, 0.f, 0.f, 0.f};
    if (ni == 0) {   // self row
        uint4 v = *(const uint4*)(hb + (size_t)node * HID);
        const ushort* u = (const ushort*)&v;
        #pragma unroll
        for (int j = 0; j < 8; j++) a[j] = bf2f(u[j]);
    }
    unsigned p0 = offs[node], p1 = offs[node + 1];
    int s0, s1, s2, s3;
    float w0, w1, w2, w3;
    #define GETC1(pos, sv, wv) { unsigned q_ = (pos); bool v_ = q_ < p1; \
        sv = v_ ? col[q_] : 0; wv = v_ ? 1.f : 0.f; }
    GETC1(p0 + ni,      s0, w0);
    GETC1(p0 + ni + 4,  s1, w1);
    GETC1(p0 + ni + 8,  s2, w2);
    GETC1(p0 + ni + 12, s3, w3);
    for (unsigned p = p0; p < p1; p += 16) {
        int n0, n1, n2, n3;
        float x0, x1, x2, x3;
        GETC1(p + 16 + ni, n0, x0);
        GETC1(p + 20 + ni, n1, x1);
        GETC1(p + 24 + ni, n2, x2);
        GETC1(p + 28 + ni, n3, x3);
        uint4 v0 = *(const uint4*)(hb + (size_t)s0 * HID);
        uint4 v1 = *(const uint4*)(hb + (size_t)s1 * HID);
        uint4 v2 = *(const uint4*)(hb + (size_t)s2 * HID);
        uint4 v3 = *(const uint4*)(hb + (size_t)s3 * HID);
        const ushort* u0 = (const ushort*)&v0;
        const ushort* u1 = (const ushort*)&v1;
        const ushort* u2 = (const ushort*)&v2;
        const ushort* u3 = (const ushort*)&v3;
        #pragma unroll
        for (int j = 0; j < 8; j++)
            a[j] += (w0 * bf2f(u0[j]) + w1 * bf2f(u1[j]))
                  + (w2 * bf2f(u2[j]) + w3 * bf2f(u3[j]));
        s0 = n0; w0 = x0; s1 = n1; w1 = x1;
        s2 = n2; w2 = x2; s3 = n3; w3 = x3;
    }
    // reduce across the 4 neighbor slots (lane bits 4,5)
    #pragma unroll
    for (int j = 0; j < 8; j++) {
        a[j] += __shfl_xor(a[j], 16);
        a[j] += __shfl_xor(a[j], 32);
    }
    if (ni == 0) {
        float dd = dis[node];
        float4 bb0 = *(const float4*)(b1 + fl * 8);
        float4 bb1 = *(const float4*)(b1 + fl * 8 + 4);
        const float bb[8] = {bb0.x, bb0.y, bb0.z, bb0.w, bb1.x, bb1.y, bb1.z, bb1.w};
        __align__(16) ushort o[8];
        #pragma unroll
        for (int j = 0; j < 8; j++) o[j] = f2bf(fmaxf(a[j] * dd + bb[j], 0.f));
        *(uint4*)(out + (size_t)node * HID + (size_t)fl * 8) = *(const uint4*)o;
    }
}

// ------- GEMM2 MFMA, W2p staged in LDS: h2s[N,48p] = (ag1 @ W2) * dis[row] --
__global__ __launch_bounds__(256) void gemm2_mfma(const ushort* __restrict__ A,
                                                  const ushort* __restrict__ W2p,
                                                  const float* __restrict__ dis,
                                                  ushort* __restrict__ h2, int N) {
    __shared__ ushort Ws[6144];   // 12 KB
    const int tid  = threadIdx.x;
    {   // stage: 6144 ushorts = 768 uint4 = 256 thr x 3
        const uint4* s = (const uint4*)W2p;
        uint4* d = (uint4*)Ws;
        #pragma unroll
        for (int r = 0; r < 3; r++) d[tid + r * 256] = s[tid + r * 256];
    }
    __syncthreads();
    const int wave = tid >> 6;
    const int lane = tid & 63;
    const int quad = lane >> 4;
    const int mr   = lane & 15;
    const int base = (blockIdx.x * 4 + wave) * 32;
    if (base >= N) return;          // safe: after the only barrier
    const int r0 = base + mr;
    const int r1 = base + 16 + mr;
    const bool ok0 = r0 < N, ok1 = r1 < N;
    const ushort* ap0 = A + (size_t)(ok0 ? r0 : 0) * HID + quad * 8;
    const ushort* ap1 = A + (size_t)(ok1 ? r1 : 0) * HID + quad * 8;
    const ushort* bp = Ws + quad * 384 + mr * 8;   // + ks*1536 + t*128

    f32x4v acc0[3], acc1[3];
    #pragma unroll
    for (int t = 0; t < 3; t++) {
        acc0[t] = (f32x4v){0.f, 0.f, 0.f, 0.f};
        acc1[t] = (f32x4v){0.f, 0.f, 0.f, 0.f};
    }
    #pragma unroll
    for (int ks = 0; ks < 4; ks++) {
        bf16x8 a0 = *(const bf16x8*)(ap0 + ks * 32);
        bf16x8 a1 = *(const bf16x8*)(ap1 + ks * 32);
        #pragma unroll
        for (int t = 0; t < 3; t++) {
            bf16x8 b = *(const bf16x8*)(bp + ks * 1536 + t * 128);
            acc0[t] = __builtin_amdgcn_mfma_f32_16x16x32_bf16(a0, b, acc0[t], 0, 0, 0);
            acc1[t] = __builtin_amdgcn_mfma_f32_16x16x32_bf16(a1, b, acc1[t], 0, 0, 0);
        }
    }
    #pragma unroll
    for (int rr = 0; rr < 4; rr++) {
        int ra = base + quad * 4 + rr;
        if (ra < N) {
            float ds = dis[ra];
            #pragma unroll
            for (int t = 0; t < 3; t++) {
                int c = t * 16 + mr;
                if (c < NC) h2[(size_t)ra * NCP + c] = f2bf(acc0[t][rr] * ds);
            }
        }
        int rb = base + 16 + quad * 4 + rr;
        if (rb < N) {
            float ds = dis[rb];
            #pragma unroll
            for (int t = 0; t < 3; t++) {
                int c = t * 16 + mr;
                if (c < NC) h2[(size_t)rb * NCP + c] = f2bf(acc1[t][rr] * ds);
            }
        }
    }
}

// ------- agg2 + b2 + log_softmax: ONE WAVE per node. lane = ni(8) x fl(8). --
__global__ __launch_bounds__(256) void agg2_ls(const ushort* __restrict__ h2,
                                               const int* __restrict__ col,
                                               const unsigned* __restrict__ offs,
                                               const float* __restrict__ dis,
                                               const float* __restrict__ b2,
                                               float* __restrict__ out, int N) {
    int node = blockIdx.x * 4 + (threadIdx.x >> 6);
    if (node >= N) return;
    int lane = threadIdx.x & 63;
    int ni = lane >> 3;          // neighbor slot 0..7
    int fl = lane & 7;           // feature group
    const bool act = fl < 5;     // 5 x 8 = 40 classes
    const ushort* hb = h2 + (size_t)fl * 8;
    float a[8] = {0.f, 0.f, 0.f, 0.f, 0.f, 0.f, 0.f, 0.f};
    if (ni == 0 && act) {   // self row
        uint4 v = *(const uint4*)(hb + (size_t)node * NCP);
        const ushort* u = (const ushort*)&v;
        #pragma unroll
        for (int j = 0; j < 8; j++) a[j] = bf2f(u[j]);
    }
    unsigned p0 = offs[node], p1 = offs[node + 1];
    int s0, s1, s2, s3;
    float w0, w1, w2, w3;
    GETC1(p0 + ni,      s0, w0);
    GETC1(p0 + ni + 8,  s1, w1);
    GETC1(p0 + ni + 16, s2, w2);
    GETC1(p0 + ni + 24, s3, w3);
    for (unsigned p = p0; p < p1; p += 32) {
        int n0, n1, n2, n3;
        float x0, x1, x2, x3;
        GETC1(p + 32 + ni, n0, x0);
        GETC1(p + 40 + ni, n1, x1);
        GETC1(p + 48 + ni, n2, x2);
        GETC1(p + 56 + ni, n3, x3);
        if (act) {
            uint4 v0 = *(const uint4*)(hb + (size_t)s0 * NCP);
            uint4 v1 = *(const uint4*)(hb + (size_t)s1 * NCP);
            uint4 v2 = *(const uint4*)(hb + (size_t)s2 * NCP);
            uint4 v3 = *(const uint4*)(hb + (size_t)s3 * NCP);
            const ushort* u0 = (const ushort*)&v0;
            const ushort* u1 = (const ushort*)&v1;
            const ushort* u2 = (const ushort*)&v2;
            const ushort* u3 = (const ushort*)&v3;
            #pragma unroll
            for (int j = 0; j < 8; j++)
                a[j] += (w0 * bf2f(u0[j]) + w1 * bf2f(u1[j]))
                      + (w2 * bf2f(u2[j]) + w3 * bf2f(u3[j]));
        }
        s0 = n0; w0 = x0; s1 = n1; w1 = x1;
        s2 = n2; w2 = x2; s3 = n3; w3 = x3;
    }
    // reduce across the 8 neighbor slots (lane bits 3,4,5)
    #pragma unroll
    for (int j = 0; j < 8; j++) {
        a[j] += __shfl_xor(a[j], 8);
        a[j] += __shfl_xor(a[j], 16);
        a[j] += __shfl_xor(a[j], 32);
    }
    float dd = dis[node];
    float l[8];
    float m = -1e30f;
    if (act) {
        #pragma unroll
        for (int j = 0; j < 8; j++) {
            l[j] = a[j] * dd + b2[fl * 8 + j];
            m = fmaxf(m, l[j]);
        }
    }
    #pragma unroll
    for (int d = 1; d < 8; d <<= 1) m = fmaxf(m, __shfl_xor(m, d, 8));
    float s = 0.f;
    if (act) {
        #pragma unroll
        for (int j = 0; j < 8; j++) s += __expf(l[j] - m);
    }
    #pragma unroll
    for (int d = 1; d < 8; d <<= 1) s += __shfl_xor(s, d, 8);
    float lse = m + __logf(s);
    if (ni == 0 && act) {
        float* op = out + (size_t)node * NC + fl * 8;
        *(float4*)op       = make_float4(l[0]-lse, l[1]-lse, l[2]-lse, l[3]-lse);
        *(float4*)(op + 4) = make_float4(l[4]-lse, l[5]-lse, l[6]-lse, l[7]-lse);
    }
}

extern "C" void kernel_launch(void* const* d_in, const int* in_sizes, int n_in,
                              void* d_out, int out_size, void* d_ws, size_t ws_size,
                              hipStream_t stream) {
    const float* x  = (const float*)d_in[0];
    const int*   ei = (const int*)d_in[1];
    const float* W1 = (const float*)d_in[2];
    const float* b1 = (const float*)d_in[3];
    const float* W2 = (const float*)d_in[4];
    const float* b2 = (const float*)d_in[5];
    float* out = (float*)d_out;

    const int N = in_sizes[0] / F_IN;     // 100000
    const int E = in_sizes[1] / 2;        // 1600000
    const int* src = ei;
    const int* dst = ei + E;

    // ---- workspace layout ----
    char* ws = (char*)d_ws;
    size_t o = 0;
    unsigned* cnt  = (unsigned*)(ws + o); o += (size_t)N * 4;
    float*    dis  = (float*)   (ws + o); o += (size_t)N * 4;
    unsigned* offs = (unsigned*)(ws + o); o += (size_t)(N + 4) * 4;
    unsigned* bsums= (unsigned*)(ws + o); o += 4096;
    int*      rank = (int*)     (ws + o); o += (size_t)E * 4;            // 6.4 MB
    int*      col  = (int*)     (ws + o); o += (size_t)E * 4;            // 6.4 MB
    o = (o + 15) & ~(size_t)15;
    ushort*   W1p  = (ushort*)  (ws + o); o += (size_t)F_IN * HID * 2;   // 128 KB
    o = (o + 15) & ~(size_t)15;
    ushort*   W2p  = (ushort*)  (ws + o); o += 6144 * 2;                 // 12 KB
    o = (o + 15) & ~(size_t)15;
    ushort*   h1   = (ushort*)  (ws + o); o += (size_t)N * HID * 2;      // 25.6 MB
    o = (o + 15) & ~(size_t)15;
    ushort*   ag1  = (ushort*)  (ws + o); o += (size_t)N * HID * 2;      // 25.6 MB
    o = (o + 15) & ~(size_t)15;
    ushort*   h2   = (ushort*)  (ws + o); o += (size_t)N * NCP * 2;      // 9.6 MB

    const int nb = (N + 1023) / 1024;
    const int EB = (E + 255) / 256;
    const int PB = (65536 + 6144 + 255) / 256;   // 280 pack blocks
    const int GB = (N + 255) / 256;              // gemm1 blocks (256 rows each)

    // T = GB + F with F = T/3 fill blocks at bid%3==2
    int T = GB + GB / 2;
    while (T - T / 3 < GB) ++T;
    while (T - T / 3 > GB) --T;
    const int F = T / 3;

    // degree count (with rank capture) + weight pack in one launch
    hipMemsetAsync(cnt, 0, (size_t)N * 4, stream);
    prep_k<<<EB + PB, 256, 0, stream>>>(dst, E, EB, cnt, rank, W1, W2, W1p, W2p);
    scan_block<<<nb, 1024, 0, stream>>>(cnt, offs, bsums, dis, N);
    scan_add2<<<nb, 1024, 0, stream>>>(offs, bsums, N, (unsigned)E);

    // CSR fill (atomic-free, grid-stride) + layer-1 GEMM (B in LDS), merged
    fillg1<<<T, 1024, 0, stream>>>(src, dst, offs, rank, col, E, F,
                                   x, W1p, dis, h1, N);

    agg1_k<<<(N + 3) / 4, 256, 0, stream>>>(h1, col, offs, dis, b1, ag1, N);

    // layer 2
    gemm2_mfma<<<(N + 127) / 128, 256, 0, stream>>>(ag1, W2p, dis, h2, N);
    agg2_ls<<<(N + 3) / 4, 256, 0, stream>>>(h2, col, offs, dis, b2, out, N);
}